// Round 7
// baseline (502.758 us; speedup 1.0000x reference)
//
#include <hip/hip_runtime.h>
#include <hip/hip_bf16.h>
#include <math.h>

// MessagePassingLayer on MI355X — round 7.
// vs round 6: (a) edge_fused 512 thr / 128 edges per block — halves barrier
// events per edge, doubles gather loads in flight per phase; LDS ~78KB ->
// 2 blocks/CU = 16 waves/CU (50% occ). (b) upd zeroing folded into
// node_fused y==0 blocks (memset launch removed).

typedef __bf16 bf16x8 __attribute__((ext_vector_type(8)));
typedef float floatx4 __attribute__((ext_vector_type(4)));

#define LN_EPS 1e-5f

__device__ __forceinline__ unsigned short f2bf(float x) {
  unsigned int u = __float_as_uint(x);
  u = u + 0x7fffu + ((u >> 16) & 1u);
  return (unsigned short)(u >> 16);
}

__device__ __forceinline__ float bf2f(unsigned short s) {
  return __uint_as_float(((unsigned int)s) << 16);
}

__device__ __forceinline__ float geluf(float x) {
  // tanh-form gelu = x*sigmoid(u); exp2 with log2e folded into constants.
  float t = x * x;
  float u = x * (2.3022080f + 0.1029434f * t);
  float e = __builtin_amdgcn_exp2f(-u);
  return x * __builtin_amdgcn_rcpf(1.0f + e);
}

__device__ __forceinline__ float sigmoidf_fast(float x) {
  float e = __builtin_amdgcn_exp2f(-1.44269504f * x);
  return __builtin_amdgcn_rcpf(1.0f + e);
}

// ---------------------------------------------------------------------------
// prep: 9 [128,128] fp32 weights -> bf16 [n][k] (transposed). 36 blocks.
// slots: 0 WsrcT 1 WdstT 2 W1aT 3 W1bT 4 W2T 5 W3T 6 Wg1aT 7 Wg1bT 8 WoutT
// ---------------------------------------------------------------------------
__global__ __launch_bounds__(256) void prep_weights(
    const float* w0, const float* w1, const float* w2, const float* w3,
    const float* w4, const float* w5, const float* w6, const float* w7,
    const float* w8, unsigned short* out) {
  const float* srcs[9] = {w0, w1, w2, w3, w4, w5, w6, w7, w8};
  int m = blockIdx.x >> 2, c = blockIdx.x & 3;
  const float* src = srcs[m] + c * 32 * 128;
  __shared__ unsigned short sT[128][35];
  int tid = threadIdx.x;

  for (int it = 0; it < 4; ++it) {
    int f4 = tid + it * 256;
    float4 v = ((const float4*)src)[f4];
    int krel = f4 >> 5;
    int n0 = (f4 & 31) * 4;
    sT[n0 + 0][krel] = f2bf(v.x);
    sT[n0 + 1][krel] = f2bf(v.y);
    sT[n0 + 2][krel] = f2bf(v.z);
    sT[n0 + 3][krel] = f2bf(v.w);
  }
  __syncthreads();
  unsigned short* dst = out + m * 16384 + c * 32;
  for (int it = 0; it < 2; ++it) {
    int ch = tid + it * 256;
    int n = ch >> 2, kc = (ch & 3) * 8;
    unsigned short tmp[8];
    for (int j = 0; j < 8; ++j) tmp[j] = sT[n][kc + j];
    *(int4*)(dst + n * 128 + kc) = *(const int4*)tmp;
  }
}

#define LDB(pB, B)                                              \
  do {                                                          \
    const unsigned short* _p = (pB);                            \
    for (int kb = 0; kb < 4; ++kb) {                            \
      B[0][kb] = *(const bf16x8*)(_p + kb * 32);                \
      B[1][kb] = *(const bf16x8*)(_p + 2048 + kb * 32);         \
    }                                                           \
  } while (0)

// ---------------------------------------------------------------------------
// node_fused: blockIdx.y=0 -> SrcCat = [src_h@W1a+b1 | src_h@Wg1a+bg1]
//             blockIdx.y=1 -> DstCat = [dst_h@W1b    | dst_h@Wg1b    ]
// y==0 blocks also zero their 64 rows of upd (replaces memset launch).
// ---------------------------------------------------------------------------
__global__ __launch_bounds__(256, 4) void node_fused(
    const float* __restrict__ feat, const unsigned short* __restrict__ wT,
    const float* __restrict__ b_src, const float* __restrict__ b_dst,
    const float* __restrict__ b1, const float* __restrict__ bg1,
    unsigned short* __restrict__ SrcCat, unsigned short* __restrict__ DstCat,
    float* __restrict__ upd, int M) {
  __shared__ __align__(16) unsigned short sF[64][136];
  __shared__ __align__(16) unsigned short sT[64][136];
  int tid = threadIdx.x;
  int r0 = blockIdx.x * 64;
  int y = blockIdx.y;

  if (y == 0) {  // zero upd rows [r0, r0+64) — overlaps with staging
    float4 z = {0.f, 0.f, 0.f, 0.f};
    float4* p = (float4*)(upd + (long long)r0 * 128);
    for (int it = 0; it < 8; ++it) {
      int idx = tid + it * 256;           // 2048 float4 per tile
      if (r0 + (idx >> 5) < M) p[idx] = z;
    }
  }

  {  // stage feat
    int r = tid >> 2, seg = tid & 3;
    int row = r0 + r;
    const float* src = feat + (long long)row * 128;
    for (int it = 0; it < 4; ++it) {
      int c = (seg * 4 + it) * 8;
      unsigned short tmp[8];
      if (row < M) {
        float4 f0 = *(const float4*)(src + c);
        float4 f1 = *(const float4*)(src + c + 4);
        tmp[0] = f2bf(f0.x); tmp[1] = f2bf(f0.y); tmp[2] = f2bf(f0.z); tmp[3] = f2bf(f0.w);
        tmp[4] = f2bf(f1.x); tmp[5] = f2bf(f1.y); tmp[6] = f2bf(f1.z); tmp[7] = f2bf(f1.w);
      } else {
        for (int j = 0; j < 8; ++j) tmp[j] = 0;
      }
      *(int4*)&sF[r][c] = *(const int4*)tmp;
    }
  }
  __syncthreads();  // B1: feat staged

  int w = tid >> 6, lane = tid & 63, lr = lane & 15, q = lane >> 4;
  int c0 = 32 * w + lr, c1 = 32 * w + 16 + lr;
  const unsigned short* pB = wT + c0 * 128 + q * 8;

  const unsigned short* wH = pB + (y ? 1 : 0) * 16384;
  const unsigned short* wA = pB + (y ? 3 : 2) * 16384;
  const unsigned short* wG = pB + (y ? 7 : 6) * 16384;
  unsigned short* Cat = y ? DstCat : SrcCat;
  float hb0 = y ? b_dst[c0] : b_src[c0];
  float hb1 = y ? b_dst[c1] : b_src[c1];
  float ab0 = y ? 0.f : b1[c0];
  float ab1 = y ? 0.f : b1[c1];
  float gb0 = y ? 0.f : bg1[c0];
  float gb1 = y ? 0.f : bg1[c1];

  bf16x8 B[2][4];
  floatx4 acc[4][2];

  auto zacc = [&]() {
    for (int mb = 0; mb < 4; ++mb)
      for (int nb = 0; nb < 2; ++nb) acc[mb][nb] = (floatx4){0.f, 0.f, 0.f, 0.f};
  };
  auto pass = [&](const unsigned short (*Ab)[136]) {
    for (int kb = 0; kb < 4; ++kb) {
      int k = kb * 32 + q * 8;
      for (int mb = 0; mb < 4; ++mb) {
        bf16x8 a = *(const bf16x8*)&Ab[16 * mb + lr][k];
        acc[mb][0] = __builtin_amdgcn_mfma_f32_16x16x32_bf16(a, B[0][kb], acc[mb][0], 0, 0, 0);
        acc[mb][1] = __builtin_amdgcn_mfma_f32_16x16x32_bf16(a, B[1][kb], acc[mb][1], 0, 0, 0);
      }
    }
  };
  auto toGlobal = [&](float bv0, float bv1, int half) {
    for (int mb = 0; mb < 4; ++mb)
      for (int i = 0; i < 4; ++i) {
        int row = r0 + 16 * mb + 4 * q + i;
        if (row < M) {
          long long base = (long long)row * 256 + half + c0;
          Cat[base] = f2bf(acc[mb][0][i] + bv0);
          Cat[base + 16] = f2bf(acc[mb][1][i] + bv1);
        }
      }
  };

  LDB(wH, B); zacc(); pass(sF);
  for (int mb = 0; mb < 4; ++mb)
    for (int i = 0; i < 4; ++i) {
      int r = 16 * mb + 4 * q + i;
      sT[r][c0] = f2bf(acc[mb][0][i] + hb0);
      sT[r][c1] = f2bf(acc[mb][1][i] + hb1);
    }
  __syncthreads();  // B2: h tile visible

  LDB(wA, B); zacc(); pass(sT); toGlobal(ab0, ab1, 0);
  LDB(wG, B); zacc(); pass(sT); toGlobal(gb0, gb1, 128);
}

// ---------------------------------------------------------------------------
// out GEMM: d_out = upd@Wout + b_out (fp32 in, fp32 out)
// ---------------------------------------------------------------------------
__global__ __launch_bounds__(256, 4) void gemm_out(
    const float* __restrict__ A, const unsigned short* __restrict__ Bt,
    const float* __restrict__ bias, float* __restrict__ C, int M) {
  __shared__ __align__(16) unsigned short sA[64][136];
  int tid = threadIdx.x;
  int r0 = blockIdx.x * 64;

  {
    int r = tid >> 2, seg = tid & 3;
    int row = r0 + r;
    const float* src = A + (long long)row * 128;
    for (int it = 0; it < 4; ++it) {
      int c = (seg * 4 + it) * 8;
      unsigned short tmp[8];
      if (row < M) {
        float4 f0 = *(const float4*)(src + c);
        float4 f1 = *(const float4*)(src + c + 4);
        tmp[0] = f2bf(f0.x); tmp[1] = f2bf(f0.y); tmp[2] = f2bf(f0.z); tmp[3] = f2bf(f0.w);
        tmp[4] = f2bf(f1.x); tmp[5] = f2bf(f1.y); tmp[6] = f2bf(f1.z); tmp[7] = f2bf(f1.w);
      } else {
        for (int j = 0; j < 8; ++j) tmp[j] = 0;
      }
      *(int4*)&sA[r][c] = *(const int4*)tmp;
    }
  }
  __syncthreads();

  int w = tid >> 6, lane = tid & 63, lr = lane & 15, q = lane >> 4;
  const unsigned short* pB = Bt + (32 * w + lr) * 128 + q * 8;

  bf16x8 B[2][4];
  LDB(pB, B);
  floatx4 acc[4][2];
  for (int mb = 0; mb < 4; ++mb)
    for (int nb = 0; nb < 2; ++nb) acc[mb][nb] = (floatx4){0.f, 0.f, 0.f, 0.f};
  for (int kb = 0; kb < 4; ++kb) {
    int k = kb * 32 + q * 8;
    for (int mb = 0; mb < 4; ++mb) {
      bf16x8 a = *(const bf16x8*)&sA[16 * mb + lr][k];
      acc[mb][0] = __builtin_amdgcn_mfma_f32_16x16x32_bf16(a, B[0][kb], acc[mb][0], 0, 0, 0);
      acc[mb][1] = __builtin_amdgcn_mfma_f32_16x16x32_bf16(a, B[1][kb], acc[mb][1], 0, 0, 0);
    }
  }
  float bv0 = bias[32 * w + lr], bv1 = bias[32 * w + 16 + lr];
  for (int mb = 0; mb < 4; ++mb)
    for (int i = 0; i < 4; ++i) {
      int row = r0 + 16 * mb + 4 * q + i;
      if (row < M) {
        long long base = (long long)row * 128 + 32 * w + lr;
        C[base] = acc[mb][0][i] + bv0;
        C[base + 16] = acc[mb][1][i] + bv1;
      }
    }
}

// ---------------------------------------------------------------------------
// edge_fused: 128 edges/block, 512 threads / 8 waves. Wave w: row half
// g=w>>2 (rows [64g,64g+64)), col group wc=w&3 (cols [32wc,32wc+32)).
// Gather [A1|P],[B1|Q]; h1=gelu(A1+B1), gate partial during gather; 2 MFMA
// passes (W2,W3); LN; gated atomic scatter. 4 barriers.
// ---------------------------------------------------------------------------
__global__ __launch_bounds__(512, 2) void edge_fused(
    const unsigned short* __restrict__ SrcCat, const unsigned short* __restrict__ DstCat,
    const int* __restrict__ edge_src, const int* __restrict__ edge_dst,
    const unsigned short* __restrict__ wT,
    const float* __restrict__ b2, const float* __restrict__ b3,
    const float* __restrict__ ln_g, const float* __restrict__ ln_b,
    const float* __restrict__ Wg2, const float* __restrict__ bg2,
    float* __restrict__ upd, int E) {
  __shared__ __align__(16) unsigned short sH1[128][136];
  __shared__ __align__(16) unsigned short sH2[128][136];
  __shared__ int sDst[128];
  __shared__ float sGp[128][4];
  __shared__ float sGate[128];
  __shared__ float sR1[4][128];
  __shared__ float sR2[4][128];
  __shared__ float sM[128];
  __shared__ float sRS[128];

  int tid = threadIdx.x;
  int e0 = blockIdx.x * 128;

  {  // gather + h1 + gate partial. 4 threads/row; seg owns cols [32s,32s+32)
    int r = tid >> 2, seg = tid & 3;
    int e = e0 + r;
    int ee = (e < E) ? e : (E - 1);
    int es = edge_src[ee], ed = edge_dst[ee];
    if (seg == 0) sDst[r] = (e < E) ? ed : -1;
    const unsigned short* ps = SrcCat + (long long)es * 256 + seg * 32;
    const unsigned short* pd = DstCat + (long long)ed * 256 + seg * 32;

    int4 sa[4], sb[4], ga[4], gb[4];
    for (int u = 0; u < 4; ++u) {
      sa[u] = ((const int4*)ps)[u];
      sb[u] = ((const int4*)pd)[u];
      ga[u] = ((const int4*)(ps + 128))[u];
      gb[u] = ((const int4*)(pd + 128))[u];
    }
    for (int u = 0; u < 4; ++u) {
      const unsigned short* av = (const unsigned short*)&sa[u];
      const unsigned short* bv = (const unsigned short*)&sb[u];
      unsigned short outv[8];
      for (int j = 0; j < 8; ++j)
        outv[j] = f2bf(geluf(bf2f(av[j]) + bf2f(bv[j])));
      *(int4*)&sH1[r][seg * 32 + u * 8] = *(const int4*)outv;
    }
    float gp = 0.f;
    for (int u = 0; u < 4; ++u) {
      const unsigned short* av = (const unsigned short*)&ga[u];
      const unsigned short* bv = (const unsigned short*)&gb[u];
      float4 w0 = *(const float4*)(Wg2 + seg * 32 + u * 8);
      float4 w1 = *(const float4*)(Wg2 + seg * 32 + u * 8 + 4);
      gp += geluf(bf2f(av[0]) + bf2f(bv[0])) * w0.x;
      gp += geluf(bf2f(av[1]) + bf2f(bv[1])) * w0.y;
      gp += geluf(bf2f(av[2]) + bf2f(bv[2])) * w0.z;
      gp += geluf(bf2f(av[3]) + bf2f(bv[3])) * w0.w;
      gp += geluf(bf2f(av[4]) + bf2f(bv[4])) * w1.x;
      gp += geluf(bf2f(av[5]) + bf2f(bv[5])) * w1.y;
      gp += geluf(bf2f(av[6]) + bf2f(bv[6])) * w1.z;
      gp += geluf(bf2f(av[7]) + bf2f(bv[7])) * w1.w;
    }
    sGp[r][seg] = gp;
  }
  __syncthreads();  // B1: sH1 + sGp + sDst visible

  if (tid < 128) {
    float g = sGp[tid][0] + sGp[tid][1] + sGp[tid][2] + sGp[tid][3] + bg2[0];
    sGate[tid] = sigmoidf_fast(g);  // read after B4
  }

  int w = tid >> 6, lane = tid & 63, lr = lane & 15, q = lane >> 4;
  int g = w >> 2, wc = w & 3;
  int rbase = 64 * g;
  int c0 = 32 * wc + lr, c1 = 32 * wc + 16 + lr;
  const unsigned short* pB = wT + c0 * 128 + q * 8;

  bf16x8 B[2][4];
  floatx4 acc[4][2];
  auto zacc = [&]() {
    for (int mb = 0; mb < 4; ++mb)
      for (int nb = 0; nb < 2; ++nb) acc[mb][nb] = (floatx4){0.f, 0.f, 0.f, 0.f};
  };
  auto pass = [&](const unsigned short (*Ab)[136]) {
    for (int kb = 0; kb < 4; ++kb) {
      int k = kb * 32 + q * 8;
      for (int mb = 0; mb < 4; ++mb) {
        bf16x8 a = *(const bf16x8*)&Ab[rbase + 16 * mb + lr][k];
        acc[mb][0] = __builtin_amdgcn_mfma_f32_16x16x32_bf16(a, B[0][kb], acc[mb][0], 0, 0, 0);
        acc[mb][1] = __builtin_amdgcn_mfma_f32_16x16x32_bf16(a, B[1][kb], acc[mb][1], 0, 0, 0);
      }
    }
  };

  // ---- stage 2: h2 = gelu(h1@W2 + b2) -> sH2 ----
  LDB(pB + 4 * 16384, B);
  zacc();
  pass(sH1);
  {
    float bv0 = b2[c0], bv1 = b2[c1];
    for (int mb = 0; mb < 4; ++mb)
      for (int i = 0; i < 4; ++i) {
        int r = rbase + 16 * mb + 4 * q + i;
        sH2[r][c0] = f2bf(geluf(acc[mb][0][i] + bv0));
        sH2[r][c1] = f2bf(geluf(acc[mb][1][i] + bv1));
      }
  }
  __syncthreads();  // B2: sH2 visible

  // ---- stage 3: x = h2@W3 + b3 ; LN partials ----
  LDB(pB + 5 * 16384, B);
  zacc();
  pass(sH2);
  {
    float bv0 = b3[c0], bv1 = b3[c1];
    for (int mb = 0; mb < 4; ++mb)
      for (int i = 0; i < 4; ++i) {
        float x0 = acc[mb][0][i] + bv0;
        float x1 = acc[mb][1][i] + bv1;
        acc[mb][0][i] = x0; acc[mb][1][i] = x1;
        float s = x0 + x1, s2 = x0 * x0 + x1 * x1;
        s += __shfl_xor(s, 1); s += __shfl_xor(s, 2);
        s += __shfl_xor(s, 4); s += __shfl_xor(s, 8);
        s2 += __shfl_xor(s2, 1); s2 += __shfl_xor(s2, 2);
        s2 += __shfl_xor(s2, 4); s2 += __shfl_xor(s2, 8);
        if (lr == 0) {
          int r = rbase + 16 * mb + 4 * q + i;
          sR1[wc][r] = s; sR2[wc][r] = s2;
        }
      }
  }
  __syncthreads();  // B3: LN partials visible
  if (tid < 128) {
    float s = sR1[0][tid] + sR1[1][tid] + sR1[2][tid] + sR1[3][tid];
    float s2 = sR2[0][tid] + sR2[1][tid] + sR2[2][tid] + sR2[3][tid];
    float m = s * (1.f / 128.f);
    float v = s2 * (1.f / 128.f) - m * m;
    sM[tid] = m;
    sRS[tid] = rsqrtf(v + LN_EPS);
  }
  __syncthreads();  // B4: stats + sGate visible

  {
    float lg0 = ln_g[c0], lg1 = ln_g[c1];
    float lb0 = ln_b[c0], lb1 = ln_b[c1];
    for (int mb = 0; mb < 4; ++mb)
      for (int i = 0; i < 4; ++i) {
        int r = rbase + 16 * mb + 4 * q + i;
        int dst = sDst[r];
        if (dst >= 0) {
          float m = sM[r], rs = sRS[r], gt = sGate[r];
          float v0 = ((acc[mb][0][i] - m) * rs * lg0 + lb0) * gt;
          float v1 = ((acc[mb][1][i] - m) * rs * lg1 + lb1) * gt;
          float* base = upd + (long long)dst * 128;
          unsafeAtomicAdd(base + c0, v0);
          unsafeAtomicAdd(base + c1, v1);
        }
      }
  }
}

// ---------------------------------------------------------------------------
extern "C" void kernel_launch(void* const* d_in, const int* in_sizes, int n_in,
                              void* d_out, int out_size, void* d_ws, size_t ws_size,
                              hipStream_t stream) {
  const float* feat   = (const float*)d_in[0];
  const int* edge_src = (const int*)d_in[1];
  const int* edge_dst = (const int*)d_in[2];
  const float* W_src = (const float*)d_in[3];  const float* b_src = (const float*)d_in[4];
  const float* W_dst = (const float*)d_in[5];  const float* b_dst = (const float*)d_in[6];
  const float* W1a = (const float*)d_in[7];    const float* W1b = (const float*)d_in[8];
  const float* b1  = (const float*)d_in[9];
  const float* W2  = (const float*)d_in[10];   const float* b2  = (const float*)d_in[11];
  const float* W3  = (const float*)d_in[12];   const float* b3  = (const float*)d_in[13];
  const float* ln_g = (const float*)d_in[14];  const float* ln_b = (const float*)d_in[15];
  const float* Wg1a = (const float*)d_in[16];  const float* Wg1b = (const float*)d_in[17];
  const float* bg1  = (const float*)d_in[18];
  const float* Wg2  = (const float*)d_in[19];  const float* bg2 = (const float*)d_in[20];
  const float* W_out = (const float*)d_in[21]; const float* b_out = (const float*)d_in[22];

  int N = in_sizes[0] / 128;   // 100000
  int E = in_sizes[1];         // 400000

  // ws layout: [wT 288KB][SrcCat bf16 N*256][DstCat bf16 N*256][upd fp32 N*128]
  char* ws = (char*)d_ws;
  unsigned short* wT = (unsigned short*)ws;
  size_t off = 9 * 16384 * sizeof(unsigned short);
  unsigned short* SrcCat = (unsigned short*)(ws + off);
  off += (size_t)N * 256 * sizeof(unsigned short);
  unsigned short* DstCat = (unsigned short*)(ws + off);
  off += (size_t)N * 256 * sizeof(unsigned short);
  float* upd = (float*)(ws + off);

  prep_weights<<<36, 256, 0, stream>>>(W_src, W_dst, W1a, W1b, W2, W3, Wg1a, Wg1b,
                                       W_out, wT);
  int mtiles = (N + 63) / 64;
  node_fused<<<dim3(mtiles, 2), 256, 0, stream>>>(feat, wT, b_src, b_dst, b1, bg1,
                                                  SrcCat, DstCat, upd, N);
  edge_fused<<<(E + 127) / 128, 512, 0, stream>>>(SrcCat, DstCat, edge_src, edge_dst,
                                                  wT, b2, b3, ln_g, ln_b, Wg2, bg2,
                                                  upd, E);
  gemm_out<<<mtiles, 256, 0, stream>>>(upd, wT + 8 * 16384, b_out, (float*)d_out, N);
}

// Round 8
// 382.898 us; speedup vs baseline: 1.3130x; 1.3130x over previous
//
#include <hip/hip_runtime.h>
#include <hip/hip_bf16.h>
#include <math.h>

// MessagePassingLayer on MI355X — round 8.
// vs round 6 (best edge config: 256 thr / 64 edges, 4 blocks/CU):
// (a) scatter uses global_atomic_pk_add_bf16 — 2 bf16 per atomic, halves
//     lane-atomic count 51.2M -> 25.6M (theory: L2 atomic-unit throughput
//     ~307G/s is the edge kernel's floor). Lanes pair via shfl_xor(1).
// (b) upd is bf16 [N,128]: node_fused zeroes it, gemm_out reads it directly.
// Round-7's 512-thr edge block REGRESSED (fewer barrier domains/CU) — reverted.

typedef __bf16 bf16x8 __attribute__((ext_vector_type(8)));
typedef float floatx4 __attribute__((ext_vector_type(4)));

#define LN_EPS 1e-5f

__device__ __forceinline__ unsigned short f2bf(float x) {
  unsigned int u = __float_as_uint(x);
  u = u + 0x7fffu + ((u >> 16) & 1u);
  return (unsigned short)(u >> 16);
}

__device__ __forceinline__ float bf2f(unsigned short s) {
  return __uint_as_float(((unsigned int)s) << 16);
}

__device__ __forceinline__ float geluf(float x) {
  // tanh-form gelu = x*sigmoid(u); exp2 with log2e folded into constants.
  float t = x * x;
  float u = x * (2.3022080f + 0.1029434f * t);
  float e = __builtin_amdgcn_exp2f(-u);
  return x * __builtin_amdgcn_rcpf(1.0f + e);
}

__device__ __forceinline__ float sigmoidf_fast(float x) {
  float e = __builtin_amdgcn_exp2f(-1.44269504f * x);
  return __builtin_amdgcn_rcpf(1.0f + e);
}

// ---------------------------------------------------------------------------
// prep: 9 [128,128] fp32 weights -> bf16 [n][k] (transposed). 36 blocks.
// slots: 0 WsrcT 1 WdstT 2 W1aT 3 W1bT 4 W2T 5 W3T 6 Wg1aT 7 Wg1bT 8 WoutT
// ---------------------------------------------------------------------------
__global__ __launch_bounds__(256) void prep_weights(
    const float* w0, const float* w1, const float* w2, const float* w3,
    const float* w4, const float* w5, const float* w6, const float* w7,
    const float* w8, unsigned short* out) {
  const float* srcs[9] = {w0, w1, w2, w3, w4, w5, w6, w7, w8};
  int m = blockIdx.x >> 2, c = blockIdx.x & 3;
  const float* src = srcs[m] + c * 32 * 128;
  __shared__ unsigned short sT[128][35];
  int tid = threadIdx.x;

  for (int it = 0; it < 4; ++it) {
    int f4 = tid + it * 256;
    float4 v = ((const float4*)src)[f4];
    int krel = f4 >> 5;
    int n0 = (f4 & 31) * 4;
    sT[n0 + 0][krel] = f2bf(v.x);
    sT[n0 + 1][krel] = f2bf(v.y);
    sT[n0 + 2][krel] = f2bf(v.z);
    sT[n0 + 3][krel] = f2bf(v.w);
  }
  __syncthreads();
  unsigned short* dst = out + m * 16384 + c * 32;
  for (int it = 0; it < 2; ++it) {
    int ch = tid + it * 256;
    int n = ch >> 2, kc = (ch & 3) * 8;
    unsigned short tmp[8];
    for (int j = 0; j < 8; ++j) tmp[j] = sT[n][kc + j];
    *(int4*)(dst + n * 128 + kc) = *(const int4*)tmp;
  }
}

#define LDB(pB, B)                                              \
  do {                                                          \
    const unsigned short* _p = (pB);                            \
    for (int kb = 0; kb < 4; ++kb) {                            \
      B[0][kb] = *(const bf16x8*)(_p + kb * 32);                \
      B[1][kb] = *(const bf16x8*)(_p + 2048 + kb * 32);         \
    }                                                           \
  } while (0)

// ---------------------------------------------------------------------------
// node_fused: blockIdx.y=0 -> SrcCat = [src_h@W1a+b1 | src_h@Wg1a+bg1]
//             blockIdx.y=1 -> DstCat = [dst_h@W1b    | dst_h@Wg1b    ]
// y==0 blocks also zero their 64 rows of upd (bf16).
// ---------------------------------------------------------------------------
__global__ __launch_bounds__(256, 4) void node_fused(
    const float* __restrict__ feat, const unsigned short* __restrict__ wT,
    const float* __restrict__ b_src, const float* __restrict__ b_dst,
    const float* __restrict__ b1, const float* __restrict__ bg1,
    unsigned short* __restrict__ SrcCat, unsigned short* __restrict__ DstCat,
    unsigned short* __restrict__ upd, int M) {
  __shared__ __align__(16) unsigned short sF[64][136];
  __shared__ __align__(16) unsigned short sT[64][136];
  int tid = threadIdx.x;
  int r0 = blockIdx.x * 64;
  int y = blockIdx.y;

  if (y == 0) {  // zero upd rows [r0, r0+64): 64*128 bf16 = 1024 int4
    int4 z = {0, 0, 0, 0};
    int4* p = (int4*)(upd + (long long)r0 * 128);
    for (int it = 0; it < 4; ++it) {
      int idx = tid + it * 256;          // 16 int4 per row
      if (r0 + (idx >> 4) < M) p[idx] = z;
    }
  }

  {  // stage feat
    int r = tid >> 2, seg = tid & 3;
    int row = r0 + r;
    const float* src = feat + (long long)row * 128;
    for (int it = 0; it < 4; ++it) {
      int c = (seg * 4 + it) * 8;
      unsigned short tmp[8];
      if (row < M) {
        float4 f0 = *(const float4*)(src + c);
        float4 f1 = *(const float4*)(src + c + 4);
        tmp[0] = f2bf(f0.x); tmp[1] = f2bf(f0.y); tmp[2] = f2bf(f0.z); tmp[3] = f2bf(f0.w);
        tmp[4] = f2bf(f1.x); tmp[5] = f2bf(f1.y); tmp[6] = f2bf(f1.z); tmp[7] = f2bf(f1.w);
      } else {
        for (int j = 0; j < 8; ++j) tmp[j] = 0;
      }
      *(int4*)&sF[r][c] = *(const int4*)tmp;
    }
  }
  __syncthreads();  // B1: feat staged

  int w = tid >> 6, lane = tid & 63, lr = lane & 15, q = lane >> 4;
  int c0 = 32 * w + lr, c1 = 32 * w + 16 + lr;
  const unsigned short* pB = wT + c0 * 128 + q * 8;

  const unsigned short* wH = pB + (y ? 1 : 0) * 16384;
  const unsigned short* wA = pB + (y ? 3 : 2) * 16384;
  const unsigned short* wG = pB + (y ? 7 : 6) * 16384;
  unsigned short* Cat = y ? DstCat : SrcCat;
  float hb0 = y ? b_dst[c0] : b_src[c0];
  float hb1 = y ? b_dst[c1] : b_src[c1];
  float ab0 = y ? 0.f : b1[c0];
  float ab1 = y ? 0.f : b1[c1];
  float gb0 = y ? 0.f : bg1[c0];
  float gb1 = y ? 0.f : bg1[c1];

  bf16x8 B[2][4];
  floatx4 acc[4][2];

  auto zacc = [&]() {
    for (int mb = 0; mb < 4; ++mb)
      for (int nb = 0; nb < 2; ++nb) acc[mb][nb] = (floatx4){0.f, 0.f, 0.f, 0.f};
  };
  auto pass = [&](const unsigned short (*Ab)[136]) {
    for (int kb = 0; kb < 4; ++kb) {
      int k = kb * 32 + q * 8;
      for (int mb = 0; mb < 4; ++mb) {
        bf16x8 a = *(const bf16x8*)&Ab[16 * mb + lr][k];
        acc[mb][0] = __builtin_amdgcn_mfma_f32_16x16x32_bf16(a, B[0][kb], acc[mb][0], 0, 0, 0);
        acc[mb][1] = __builtin_amdgcn_mfma_f32_16x16x32_bf16(a, B[1][kb], acc[mb][1], 0, 0, 0);
      }
    }
  };
  auto toGlobal = [&](float bv0, float bv1, int half) {
    for (int mb = 0; mb < 4; ++mb)
      for (int i = 0; i < 4; ++i) {
        int row = r0 + 16 * mb + 4 * q + i;
        if (row < M) {
          long long base = (long long)row * 256 + half + c0;
          Cat[base] = f2bf(acc[mb][0][i] + bv0);
          Cat[base + 16] = f2bf(acc[mb][1][i] + bv1);
        }
      }
  };

  LDB(wH, B); zacc(); pass(sF);
  for (int mb = 0; mb < 4; ++mb)
    for (int i = 0; i < 4; ++i) {
      int r = 16 * mb + 4 * q + i;
      sT[r][c0] = f2bf(acc[mb][0][i] + hb0);
      sT[r][c1] = f2bf(acc[mb][1][i] + hb1);
    }
  __syncthreads();  // B2: h tile visible

  LDB(wA, B); zacc(); pass(sT); toGlobal(ab0, ab1, 0);
  LDB(wG, B); zacc(); pass(sT); toGlobal(gb0, gb1, 128);
}

// ---------------------------------------------------------------------------
// out GEMM: d_out = upd(bf16)@Wout + b_out (fp32 out)
// ---------------------------------------------------------------------------
__global__ __launch_bounds__(256, 4) void gemm_out(
    const unsigned short* __restrict__ A, const unsigned short* __restrict__ Bt,
    const float* __restrict__ bias, float* __restrict__ C, int M) {
  __shared__ __align__(16) unsigned short sA[64][136];
  int tid = threadIdx.x;
  int r0 = blockIdx.x * 64;

  {
    int r = tid >> 2, seg = tid & 3;
    int row = r0 + r;
    const int4* src = (const int4*)(A + (long long)row * 128);
    for (int it = 0; it < 4; ++it) {
      int c = seg * 4 + it;              // int4 index, 16 per row
      int4 v;
      if (row < M) v = src[c];
      else v = (int4){0, 0, 0, 0};
      *(int4*)&sA[r][c * 8] = v;
    }
  }
  __syncthreads();

  int w = tid >> 6, lane = tid & 63, lr = lane & 15, q = lane >> 4;
  const unsigned short* pB = Bt + (32 * w + lr) * 128 + q * 8;

  bf16x8 B[2][4];
  LDB(pB, B);
  floatx4 acc[4][2];
  for (int mb = 0; mb < 4; ++mb)
    for (int nb = 0; nb < 2; ++nb) acc[mb][nb] = (floatx4){0.f, 0.f, 0.f, 0.f};
  for (int kb = 0; kb < 4; ++kb) {
    int k = kb * 32 + q * 8;
    for (int mb = 0; mb < 4; ++mb) {
      bf16x8 a = *(const bf16x8*)&sA[16 * mb + lr][k];
      acc[mb][0] = __builtin_amdgcn_mfma_f32_16x16x32_bf16(a, B[0][kb], acc[mb][0], 0, 0, 0);
      acc[mb][1] = __builtin_amdgcn_mfma_f32_16x16x32_bf16(a, B[1][kb], acc[mb][1], 0, 0, 0);
    }
  }
  float bv0 = bias[32 * w + lr], bv1 = bias[32 * w + 16 + lr];
  for (int mb = 0; mb < 4; ++mb)
    for (int i = 0; i < 4; ++i) {
      int row = r0 + 16 * mb + 4 * q + i;
      if (row < M) {
        long long base = (long long)row * 128 + 32 * w + lr;
        C[base] = acc[mb][0][i] + bv0;
        C[base + 16] = acc[mb][1][i] + bv1;
      }
    }
}

// ---------------------------------------------------------------------------
// edge_fused: 64 edges/block, 256 thr (r6 shape). Gather [A1|P],[B1|Q];
// h1=gelu(A1+B1) + gate partial during gather; 2 MFMA passes (W2,W3); LN;
// gated scatter via global_atomic_pk_add_bf16 (2 cols per atomic).
// ---------------------------------------------------------------------------
__global__ __launch_bounds__(256, 4) void edge_fused(
    const unsigned short* __restrict__ SrcCat, const unsigned short* __restrict__ DstCat,
    const int* __restrict__ edge_src, const int* __restrict__ edge_dst,
    const unsigned short* __restrict__ wT,
    const float* __restrict__ b2, const float* __restrict__ b3,
    const float* __restrict__ ln_g, const float* __restrict__ ln_b,
    const float* __restrict__ Wg2, const float* __restrict__ bg2,
    unsigned short* __restrict__ upd, int E) {
  __shared__ __align__(16) unsigned short sH1[64][136];
  __shared__ __align__(16) unsigned short sH2[64][136];
  __shared__ int sDst[64];
  __shared__ float sGp[64][4];
  __shared__ float sGate[64];
  __shared__ float sR1[4][64];
  __shared__ float sR2[4][64];
  __shared__ float sM[64];
  __shared__ float sRS[64];

  int tid = threadIdx.x;
  int e0 = blockIdx.x * 64;

  {  // gather + h1 + gate partial. 4 threads/row; seg owns cols [32s,32s+32)
    int r = tid >> 2, seg = tid & 3;
    int e = e0 + r;
    int ee = (e < E) ? e : (E - 1);
    int es = edge_src[ee], ed = edge_dst[ee];
    if (seg == 0) sDst[r] = (e < E) ? ed : -1;
    const unsigned short* ps = SrcCat + (long long)es * 256 + seg * 32;
    const unsigned short* pd = DstCat + (long long)ed * 256 + seg * 32;

    int4 sa[4], sb[4], ga[4], gb[4];
    for (int u = 0; u < 4; ++u) {
      sa[u] = ((const int4*)ps)[u];
      sb[u] = ((const int4*)pd)[u];
      ga[u] = ((const int4*)(ps + 128))[u];
      gb[u] = ((const int4*)(pd + 128))[u];
    }
    for (int u = 0; u < 4; ++u) {
      const unsigned short* av = (const unsigned short*)&sa[u];
      const unsigned short* bv = (const unsigned short*)&sb[u];
      unsigned short outv[8];
      for (int j = 0; j < 8; ++j)
        outv[j] = f2bf(geluf(bf2f(av[j]) + bf2f(bv[j])));
      *(int4*)&sH1[r][seg * 32 + u * 8] = *(const int4*)outv;
    }
    float gp = 0.f;
    for (int u = 0; u < 4; ++u) {
      const unsigned short* av = (const unsigned short*)&ga[u];
      const unsigned short* bv = (const unsigned short*)&gb[u];
      float4 w0 = *(const float4*)(Wg2 + seg * 32 + u * 8);
      float4 w1 = *(const float4*)(Wg2 + seg * 32 + u * 8 + 4);
      gp += geluf(bf2f(av[0]) + bf2f(bv[0])) * w0.x;
      gp += geluf(bf2f(av[1]) + bf2f(bv[1])) * w0.y;
      gp += geluf(bf2f(av[2]) + bf2f(bv[2])) * w0.z;
      gp += geluf(bf2f(av[3]) + bf2f(bv[3])) * w0.w;
      gp += geluf(bf2f(av[4]) + bf2f(bv[4])) * w1.x;
      gp += geluf(bf2f(av[5]) + bf2f(bv[5])) * w1.y;
      gp += geluf(bf2f(av[6]) + bf2f(bv[6])) * w1.z;
      gp += geluf(bf2f(av[7]) + bf2f(bv[7])) * w1.w;
    }
    sGp[r][seg] = gp;
  }
  __syncthreads();  // B1: sH1 + sGp + sDst visible

  if (tid < 64) {
    float g = sGp[tid][0] + sGp[tid][1] + sGp[tid][2] + sGp[tid][3] + bg2[0];
    sGate[tid] = sigmoidf_fast(g);  // read after B4
  }

  int w = tid >> 6, lane = tid & 63, lr = lane & 15, q = lane >> 4;
  int c0 = 32 * w + lr, c1 = 32 * w + 16 + lr;
  const unsigned short* pB = wT + c0 * 128 + q * 8;

  bf16x8 B[2][4];
  floatx4 acc[4][2];
  auto zacc = [&]() {
    for (int mb = 0; mb < 4; ++mb)
      for (int nb = 0; nb < 2; ++nb) acc[mb][nb] = (floatx4){0.f, 0.f, 0.f, 0.f};
  };
  auto pass = [&](const unsigned short (*Ab)[136]) {
    for (int kb = 0; kb < 4; ++kb) {
      int k = kb * 32 + q * 8;
      for (int mb = 0; mb < 4; ++mb) {
        bf16x8 a = *(const bf16x8*)&Ab[16 * mb + lr][k];
        acc[mb][0] = __builtin_amdgcn_mfma_f32_16x16x32_bf16(a, B[0][kb], acc[mb][0], 0, 0, 0);
        acc[mb][1] = __builtin_amdgcn_mfma_f32_16x16x32_bf16(a, B[1][kb], acc[mb][1], 0, 0, 0);
      }
    }
  };

  // ---- stage 2: h2 = gelu(h1@W2 + b2) -> sH2 ----
  LDB(pB + 4 * 16384, B);
  zacc();
  pass(sH1);
  {
    float bv0 = b2[c0], bv1 = b2[c1];
    for (int mb = 0; mb < 4; ++mb)
      for (int i = 0; i < 4; ++i) {
        int r = 16 * mb + 4 * q + i;
        sH2[r][c0] = f2bf(geluf(acc[mb][0][i] + bv0));
        sH2[r][c1] = f2bf(geluf(acc[mb][1][i] + bv1));
      }
  }
  __syncthreads();  // B2: sH2 visible

  // ---- stage 3: x = h2@W3 + b3 ; LN partials ----
  LDB(pB + 5 * 16384, B);
  zacc();
  pass(sH2);
  {
    float bv0 = b3[c0], bv1 = b3[c1];
    for (int mb = 0; mb < 4; ++mb)
      for (int i = 0; i < 4; ++i) {
        float x0 = acc[mb][0][i] + bv0;
        float x1 = acc[mb][1][i] + bv1;
        acc[mb][0][i] = x0; acc[mb][1][i] = x1;
        float s = x0 + x1, s2 = x0 * x0 + x1 * x1;
        s += __shfl_xor(s, 1); s += __shfl_xor(s, 2);
        s += __shfl_xor(s, 4); s += __shfl_xor(s, 8);
        s2 += __shfl_xor(s2, 1); s2 += __shfl_xor(s2, 2);
        s2 += __shfl_xor(s2, 4); s2 += __shfl_xor(s2, 8);
        if (lr == 0) { sR1[w][16 * mb + 4 * q + i] = s; sR2[w][16 * mb + 4 * q + i] = s2; }
      }
  }
  __syncthreads();  // B3: LN partials visible
  if (tid < 64) {
    float s = sR1[0][tid] + sR1[1][tid] + sR1[2][tid] + sR1[3][tid];
    float s2 = sR2[0][tid] + sR2[1][tid] + sR2[2][tid] + sR2[3][tid];
    float m = s * (1.f / 128.f);
    float v = s2 * (1.f / 128.f) - m * m;
    sM[tid] = m;
    sRS[tid] = rsqrtf(v + LN_EPS);
  }
  __syncthreads();  // B4: stats + sGate visible

  {
    float lg0 = ln_g[c0], lg1 = ln_g[c1];
    float lb0 = ln_b[c0], lb1 = ln_b[c1];
    for (int mb = 0; mb < 4; ++mb)
      for (int i = 0; i < 4; ++i) {
        int r = 16 * mb + 4 * q + i;
        int dst = sDst[r];
        float m = sM[r], rs = sRS[r], gt = sGate[r];
        float v0 = ((acc[mb][0][i] - m) * rs * lg0 + lb0) * gt;
        float v1 = ((acc[mb][1][i] - m) * rs * lg1 + lb1) * gt;
        // pair lanes (lr even/odd) to pack adjacent columns for pk_add_bf16
        float o0 = __shfl_xor(v0, 1);   // even lane: odd neighbor's v0
        float o1 = __shfl_xor(v1, 1);   // odd lane: even neighbor's v1
        if (dst >= 0) {                 // dst uniform within the lane pair
          unsigned int pk;
          int colb;
          if ((lr & 1) == 0) {          // cols (c0, c0+1)
            pk = (unsigned int)f2bf(v0) | ((unsigned int)f2bf(o0) << 16);
            colb = c0;
          } else {                      // cols (c0+15, c0+16) = (even c1, own c1)
            pk = (unsigned int)f2bf(o1) | ((unsigned int)f2bf(v1) << 16);
            colb = c0 + 15;
          }
          unsigned short* addr = upd + (long long)dst * 128 + colb;
          asm volatile("global_atomic_pk_add_bf16 %0, %1, off"
                       :: "v"(addr), "v"(pk) : "memory");
        }
      }
  }
}

// ---------------------------------------------------------------------------
extern "C" void kernel_launch(void* const* d_in, const int* in_sizes, int n_in,
                              void* d_out, int out_size, void* d_ws, size_t ws_size,
                              hipStream_t stream) {
  const float* feat   = (const float*)d_in[0];
  const int* edge_src = (const int*)d_in[1];
  const int* edge_dst = (const int*)d_in[2];
  const float* W_src = (const float*)d_in[3];  const float* b_src = (const float*)d_in[4];
  const float* W_dst = (const float*)d_in[5];  const float* b_dst = (const float*)d_in[6];
  const float* W1a = (const float*)d_in[7];    const float* W1b = (const float*)d_in[8];
  const float* b1  = (const float*)d_in[9];
  const float* W2  = (const float*)d_in[10];   const float* b2  = (const float*)d_in[11];
  const float* W3  = (const float*)d_in[12];   const float* b3  = (const float*)d_in[13];
  const float* ln_g = (const float*)d_in[14];  const float* ln_b = (const float*)d_in[15];
  const float* Wg1a = (const float*)d_in[16];  const float* Wg1b = (const float*)d_in[17];
  const float* bg1  = (const float*)d_in[18];
  const float* Wg2  = (const float*)d_in[19];  const float* bg2 = (const float*)d_in[20];
  const float* W_out = (const float*)d_in[21]; const float* b_out = (const float*)d_in[22];

  int N = in_sizes[0] / 128;   // 100000
  int E = in_sizes[1];         // 400000

  // ws: [wT 288KB][SrcCat bf16 N*256][DstCat bf16 N*256][upd bf16 N*128]
  char* ws = (char*)d_ws;
  unsigned short* wT = (unsigned short*)ws;
  size_t off = 9 * 16384 * sizeof(unsigned short);
  unsigned short* SrcCat = (unsigned short*)(ws + off);
  off += (size_t)N * 256 * sizeof(unsigned short);
  unsigned short* DstCat = (unsigned short*)(ws + off);
  off += (size_t)N * 256 * sizeof(unsigned short);
  unsigned short* upd = (unsigned short*)(ws + off);

  prep_weights<<<36, 256, 0, stream>>>(W_src, W_dst, W1a, W1b, W2, W3, Wg1a, Wg1b,
                                       W_out, wT);
  int mtiles = (N + 63) / 64;
  node_fused<<<dim3(mtiles, 2), 256, 0, stream>>>(feat, wT, b_src, b_dst, b1, bg1,
                                                  SrcCat, DstCat, upd, N);
  edge_fused<<<(E + 63) / 64, 256, 0, stream>>>(SrcCat, DstCat, edge_src, edge_dst,
                                                wT, b2, b3, ln_g, ln_b, Wg2, bg2,
                                                upd, E);
  gemm_out<<<mtiles, 256, 0, stream>>>(upd, wT + 8 * 16384, b_out, (float*)d_out, N);
}

// Round 9
// 375.416 us; speedup vs baseline: 1.3392x; 1.0199x over previous
//
#include <hip/hip_runtime.h>
#include <hip/hip_bf16.h>
#include <math.h>

// MessagePassingLayer on MI355X — round 9.
// vs round 8: (a) node_fused epilogue rebuilt — A1/P computed into two
// register accumulator sets, staged through LDS (reusing sF/sT), then ONE
// coalesced int4 copy phase into Cat (was 64 scalar ushort stores/thread;
// r8 showed node_fused 100% memory-stalled at 1.1 TB/s, VALUBusy 1.9%).
// (b) gemm_out epilogue via fp32 LDS tile + coalesced float4 stores.
// (c) edge_fused unchanged from r8 (pk_add_bf16 scatter — WIN, WRITE halved).

typedef __bf16 bf16x8 __attribute__((ext_vector_type(8)));
typedef float floatx4 __attribute__((ext_vector_type(4)));

#define LN_EPS 1e-5f

__device__ __forceinline__ unsigned short f2bf(float x) {
  unsigned int u = __float_as_uint(x);
  u = u + 0x7fffu + ((u >> 16) & 1u);
  return (unsigned short)(u >> 16);
}

__device__ __forceinline__ float bf2f(unsigned short s) {
  return __uint_as_float(((unsigned int)s) << 16);
}

__device__ __forceinline__ float geluf(float x) {
  // tanh-form gelu = x*sigmoid(u); exp2 with log2e folded into constants.
  float t = x * x;
  float u = x * (2.3022080f + 0.1029434f * t);
  float e = __builtin_amdgcn_exp2f(-u);
  return x * __builtin_amdgcn_rcpf(1.0f + e);
}

__device__ __forceinline__ float sigmoidf_fast(float x) {
  float e = __builtin_amdgcn_exp2f(-1.44269504f * x);
  return __builtin_amdgcn_rcpf(1.0f + e);
}

// ---------------------------------------------------------------------------
// prep: 9 [128,128] fp32 weights -> bf16 [n][k] (transposed). 36 blocks.
// slots: 0 WsrcT 1 WdstT 2 W1aT 3 W1bT 4 W2T 5 W3T 6 Wg1aT 7 Wg1bT 8 WoutT
// ---------------------------------------------------------------------------
__global__ __launch_bounds__(256) void prep_weights(
    const float* w0, const float* w1, const float* w2, const float* w3,
    const float* w4, const float* w5, const float* w6, const float* w7,
    const float* w8, unsigned short* out) {
  const float* srcs[9] = {w0, w1, w2, w3, w4, w5, w6, w7, w8};
  int m = blockIdx.x >> 2, c = blockIdx.x & 3;
  const float* src = srcs[m] + c * 32 * 128;
  __shared__ unsigned short sT[128][35];
  int tid = threadIdx.x;

  for (int it = 0; it < 4; ++it) {
    int f4 = tid + it * 256;
    float4 v = ((const float4*)src)[f4];
    int krel = f4 >> 5;
    int n0 = (f4 & 31) * 4;
    sT[n0 + 0][krel] = f2bf(v.x);
    sT[n0 + 1][krel] = f2bf(v.y);
    sT[n0 + 2][krel] = f2bf(v.z);
    sT[n0 + 3][krel] = f2bf(v.w);
  }
  __syncthreads();
  unsigned short* dst = out + m * 16384 + c * 32;
  for (int it = 0; it < 2; ++it) {
    int ch = tid + it * 256;
    int n = ch >> 2, kc = (ch & 3) * 8;
    unsigned short tmp[8];
    for (int j = 0; j < 8; ++j) tmp[j] = sT[n][kc + j];
    *(int4*)(dst + n * 128 + kc) = *(const int4*)tmp;
  }
}

#define LDB(pB, B)                                              \
  do {                                                          \
    const unsigned short* _p = (pB);                            \
    for (int kb = 0; kb < 4; ++kb) {                            \
      B[0][kb] = *(const bf16x8*)(_p + kb * 32);                \
      B[1][kb] = *(const bf16x8*)(_p + 2048 + kb * 32);         \
    }                                                           \
  } while (0)

// ---------------------------------------------------------------------------
// node_fused: blockIdx.y=0 -> SrcCat = [src_h@W1a+b1 | src_h@Wg1a+bg1]
//             blockIdx.y=1 -> DstCat = [dst_h@W1b    | dst_h@Wg1b    ]
// y==0 blocks also zero their 64 rows of upd (bf16).
// Epilogue: A1 -> sF, P -> sT (after reads drain), then one coalesced
// int4 copy phase to Cat.
// ---------------------------------------------------------------------------
__global__ __launch_bounds__(256, 4) void node_fused(
    const float* __restrict__ feat, const unsigned short* __restrict__ wT,
    const float* __restrict__ b_src, const float* __restrict__ b_dst,
    const float* __restrict__ b1, const float* __restrict__ bg1,
    unsigned short* __restrict__ SrcCat, unsigned short* __restrict__ DstCat,
    unsigned short* __restrict__ upd, int M) {
  __shared__ __align__(16) unsigned short sF[64][136];
  __shared__ __align__(16) unsigned short sT[64][136];
  int tid = threadIdx.x;
  int r0 = blockIdx.x * 64;
  int y = blockIdx.y;

  if (y == 0) {  // zero upd rows [r0, r0+64): 1024 int4
    int4 z = {0, 0, 0, 0};
    int4* p = (int4*)(upd + (long long)r0 * 128);
    for (int it = 0; it < 4; ++it) {
      int idx = tid + it * 256;
      if (r0 + (idx >> 4) < M) p[idx] = z;
    }
  }

  {  // stage feat -> sF
    int r = tid >> 2, seg = tid & 3;
    int row = r0 + r;
    const float* src = feat + (long long)row * 128;
    for (int it = 0; it < 4; ++it) {
      int c = (seg * 4 + it) * 8;
      unsigned short tmp[8];
      if (row < M) {
        float4 f0 = *(const float4*)(src + c);
        float4 f1 = *(const float4*)(src + c + 4);
        tmp[0] = f2bf(f0.x); tmp[1] = f2bf(f0.y); tmp[2] = f2bf(f0.z); tmp[3] = f2bf(f0.w);
        tmp[4] = f2bf(f1.x); tmp[5] = f2bf(f1.y); tmp[6] = f2bf(f1.z); tmp[7] = f2bf(f1.w);
      } else {
        for (int j = 0; j < 8; ++j) tmp[j] = 0;
      }
      *(int4*)&sF[r][c] = *(const int4*)tmp;
    }
  }
  __syncthreads();  // B1: feat staged

  int w = tid >> 6, lane = tid & 63, lr = lane & 15, q = lane >> 4;
  int c0 = 32 * w + lr, c1 = 32 * w + 16 + lr;
  const unsigned short* pB = wT + c0 * 128 + q * 8;

  const unsigned short* wH = pB + (y ? 1 : 0) * 16384;
  const unsigned short* wA = pB + (y ? 3 : 2) * 16384;
  const unsigned short* wG = pB + (y ? 7 : 6) * 16384;
  unsigned short* Cat = y ? DstCat : SrcCat;
  float hb0 = y ? b_dst[c0] : b_src[c0];
  float hb1 = y ? b_dst[c1] : b_src[c1];
  float ab0 = y ? 0.f : b1[c0];
  float ab1 = y ? 0.f : b1[c1];
  float gb0 = y ? 0.f : bg1[c0];
  float gb1 = y ? 0.f : bg1[c1];

  bf16x8 B[2][4];

  auto pass = [&](const unsigned short (*Ab)[136], floatx4 (&acc)[4][2]) {
    for (int kb = 0; kb < 4; ++kb) {
      int k = kb * 32 + q * 8;
      for (int mb = 0; mb < 4; ++mb) {
        bf16x8 a = *(const bf16x8*)&Ab[16 * mb + lr][k];
        acc[mb][0] = __builtin_amdgcn_mfma_f32_16x16x32_bf16(a, B[0][kb], acc[mb][0], 0, 0, 0);
        acc[mb][1] = __builtin_amdgcn_mfma_f32_16x16x32_bf16(a, B[1][kb], acc[mb][1], 0, 0, 0);
      }
    }
  };

  // h = feat@W{src,dst} + b -> sT
  {
    floatx4 acc[4][2];
    for (int mb = 0; mb < 4; ++mb)
      for (int nb = 0; nb < 2; ++nb) acc[mb][nb] = (floatx4){0.f, 0.f, 0.f, 0.f};
    LDB(wH, B);
    pass(sF, acc);
    for (int mb = 0; mb < 4; ++mb)
      for (int i = 0; i < 4; ++i) {
        int r = 16 * mb + 4 * q + i;
        sT[r][c0] = f2bf(acc[mb][0][i] + hb0);
        sT[r][c1] = f2bf(acc[mb][1][i] + hb1);
      }
  }
  __syncthreads();  // B2: h tile visible; all sF reads done

  floatx4 accA[4][2], accP[4][2];
  for (int mb = 0; mb < 4; ++mb)
    for (int nb = 0; nb < 2; ++nb) {
      accA[mb][nb] = (floatx4){0.f, 0.f, 0.f, 0.f};
      accP[mb][nb] = (floatx4){0.f, 0.f, 0.f, 0.f};
    }
  LDB(wA, B);
  pass(sT, accA);
  LDB(wG, B);
  pass(sT, accP);
  __syncthreads();  // B3: all sT reads done

  // A1 -> sF, P -> sT (overwrite)
  for (int mb = 0; mb < 4; ++mb)
    for (int i = 0; i < 4; ++i) {
      int r = 16 * mb + 4 * q + i;
      sF[r][c0] = f2bf(accA[mb][0][i] + ab0);
      sF[r][c1] = f2bf(accA[mb][1][i] + ab1);
      sT[r][c0] = f2bf(accP[mb][0][i] + gb0);
      sT[r][c1] = f2bf(accP[mb][1][i] + gb1);
    }
  __syncthreads();  // B4: staged output visible

  // coalesced copy: 64 rows x 256 cols bf16 = 2048 int4, 8 per thread
  for (int it = 0; it < 8; ++it) {
    int idx = tid + it * 256;
    int row = idx >> 5, c = idx & 31;   // c in [0,32): col chunk of 8
    if (r0 + row < M) {
      const void* src = (c < 16) ? (const void*)&sF[row][c * 8]
                                 : (const void*)&sT[row][(c - 16) * 8];
      *(int4*)(Cat + (long long)(r0 + row) * 256 + c * 8) = *(const int4*)src;
    }
  }
}

// ---------------------------------------------------------------------------
// out GEMM: d_out = upd(bf16)@Wout + b_out (fp32 out), coalesced epilogue
// ---------------------------------------------------------------------------
__global__ __launch_bounds__(256, 4) void gemm_out(
    const unsigned short* __restrict__ A, const unsigned short* __restrict__ Bt,
    const float* __restrict__ bias, float* __restrict__ C, int M) {
  __shared__ __align__(16) char smem[64 * 130 * 4];  // 33280 B
  unsigned short (*sA)[136] = (unsigned short(*)[136])smem;   // staging (17 KB)
  float (*sO)[130] = (float(*)[130])smem;                     // fp32 out tile
  int tid = threadIdx.x;
  int r0 = blockIdx.x * 64;

  {
    int r = tid >> 2, seg = tid & 3;
    int row = r0 + r;
    const int4* src = (const int4*)(A + (long long)row * 128);
    for (int it = 0; it < 4; ++it) {
      int c = seg * 4 + it;
      int4 v;
      if (row < M) v = src[c];
      else v = (int4){0, 0, 0, 0};
      *(int4*)&sA[r][c * 8] = v;
    }
  }
  __syncthreads();

  int w = tid >> 6, lane = tid & 63, lr = lane & 15, q = lane >> 4;
  int c0 = 32 * w + lr, c1 = 32 * w + 16 + lr;
  const unsigned short* pB = Bt + c0 * 128 + q * 8;

  bf16x8 B[2][4];
  LDB(pB, B);
  floatx4 acc[4][2];
  for (int mb = 0; mb < 4; ++mb)
    for (int nb = 0; nb < 2; ++nb) acc[mb][nb] = (floatx4){0.f, 0.f, 0.f, 0.f};
  for (int kb = 0; kb < 4; ++kb) {
    int k = kb * 32 + q * 8;
    for (int mb = 0; mb < 4; ++mb) {
      bf16x8 a = *(const bf16x8*)&sA[16 * mb + lr][k];
      acc[mb][0] = __builtin_amdgcn_mfma_f32_16x16x32_bf16(a, B[0][kb], acc[mb][0], 0, 0, 0);
      acc[mb][1] = __builtin_amdgcn_mfma_f32_16x16x32_bf16(a, B[1][kb], acc[mb][1], 0, 0, 0);
    }
  }
  __syncthreads();  // all sA reads done before fp32 overwrite

  float bv0 = bias[c0], bv1 = bias[c1];
  for (int mb = 0; mb < 4; ++mb)
    for (int i = 0; i < 4; ++i) {
      int r = 16 * mb + 4 * q + i;
      sO[r][c0] = acc[mb][0][i] + bv0;
      sO[r][c1] = acc[mb][1][i] + bv1;
    }
  __syncthreads();  // fp32 tile visible

  // coalesced: 64 rows x 128 fp32 = 2048 float4, 8 per thread
  for (int it = 0; it < 8; ++it) {
    int idx = tid + it * 256;
    int row = idx >> 5, c = idx & 31;
    if (r0 + row < M)
      *(float4*)(C + (long long)(r0 + row) * 128 + c * 4) = *(const float4*)&sO[row][c * 4];
  }
}

// ---------------------------------------------------------------------------
// edge_fused: 64 edges/block, 256 thr (r8 version, unchanged).
// ---------------------------------------------------------------------------
__global__ __launch_bounds__(256, 4) void edge_fused(
    const unsigned short* __restrict__ SrcCat, const unsigned short* __restrict__ DstCat,
    const int* __restrict__ edge_src, const int* __restrict__ edge_dst,
    const unsigned short* __restrict__ wT,
    const float* __restrict__ b2, const float* __restrict__ b3,
    const float* __restrict__ ln_g, const float* __restrict__ ln_b,
    const float* __restrict__ Wg2, const float* __restrict__ bg2,
    unsigned short* __restrict__ upd, int E) {
  __shared__ __align__(16) unsigned short sH1[64][136];
  __shared__ __align__(16) unsigned short sH2[64][136];
  __shared__ int sDst[64];
  __shared__ float sGp[64][4];
  __shared__ float sGate[64];
  __shared__ float sR1[4][64];
  __shared__ float sR2[4][64];
  __shared__ float sM[64];
  __shared__ float sRS[64];

  int tid = threadIdx.x;
  int e0 = blockIdx.x * 64;

  {  // gather + h1 + gate partial
    int r = tid >> 2, seg = tid & 3;
    int e = e0 + r;
    int ee = (e < E) ? e : (E - 1);
    int es = edge_src[ee], ed = edge_dst[ee];
    if (seg == 0) sDst[r] = (e < E) ? ed : -1;
    const unsigned short* ps = SrcCat + (long long)es * 256 + seg * 32;
    const unsigned short* pd = DstCat + (long long)ed * 256 + seg * 32;

    int4 sa[4], sb[4], ga[4], gb[4];
    for (int u = 0; u < 4; ++u) {
      sa[u] = ((const int4*)ps)[u];
      sb[u] = ((const int4*)pd)[u];
      ga[u] = ((const int4*)(ps + 128))[u];
      gb[u] = ((const int4*)(pd + 128))[u];
    }
    for (int u = 0; u < 4; ++u) {
      const unsigned short* av = (const unsigned short*)&sa[u];
      const unsigned short* bv = (const unsigned short*)&sb[u];
      unsigned short outv[8];
      for (int j = 0; j < 8; ++j)
        outv[j] = f2bf(geluf(bf2f(av[j]) + bf2f(bv[j])));
      *(int4*)&sH1[r][seg * 32 + u * 8] = *(const int4*)outv;
    }
    float gp = 0.f;
    for (int u = 0; u < 4; ++u) {
      const unsigned short* av = (const unsigned short*)&ga[u];
      const unsigned short* bv = (const unsigned short*)&gb[u];
      float4 w0 = *(const float4*)(Wg2 + seg * 32 + u * 8);
      float4 w1 = *(const float4*)(Wg2 + seg * 32 + u * 8 + 4);
      gp += geluf(bf2f(av[0]) + bf2f(bv[0])) * w0.x;
      gp += geluf(bf2f(av[1]) + bf2f(bv[1])) * w0.y;
      gp += geluf(bf2f(av[2]) + bf2f(bv[2])) * w0.z;
      gp += geluf(bf2f(av[3]) + bf2f(bv[3])) * w0.w;
      gp += geluf(bf2f(av[4]) + bf2f(bv[4])) * w1.x;
      gp += geluf(bf2f(av[5]) + bf2f(bv[5])) * w1.y;
      gp += geluf(bf2f(av[6]) + bf2f(bv[6])) * w1.z;
      gp += geluf(bf2f(av[7]) + bf2f(bv[7])) * w1.w;
    }
    sGp[r][seg] = gp;
  }
  __syncthreads();  // B1

  if (tid < 64) {
    float g = sGp[tid][0] + sGp[tid][1] + sGp[tid][2] + sGp[tid][3] + bg2[0];
    sGate[tid] = sigmoidf_fast(g);
  }

  int w = tid >> 6, lane = tid & 63, lr = lane & 15, q = lane >> 4;
  int c0 = 32 * w + lr, c1 = 32 * w + 16 + lr;
  const unsigned short* pB = wT + c0 * 128 + q * 8;

  bf16x8 B[2][4];
  floatx4 acc[4][2];
  auto zacc = [&]() {
    for (int mb = 0; mb < 4; ++mb)
      for (int nb = 0; nb < 2; ++nb) acc[mb][nb] = (floatx4){0.f, 0.f, 0.f, 0.f};
  };
  auto pass = [&](const unsigned short (*Ab)[136]) {
    for (int kb = 0; kb < 4; ++kb) {
      int k = kb * 32 + q * 8;
      for (int mb = 0; mb < 4; ++mb) {
        bf16x8 a = *(const bf16x8*)&Ab[16 * mb + lr][k];
        acc[mb][0] = __builtin_amdgcn_mfma_f32_16x16x32_bf16(a, B[0][kb], acc[mb][0], 0, 0, 0);
        acc[mb][1] = __builtin_amdgcn_mfma_f32_16x16x32_bf16(a, B[1][kb], acc[mb][1], 0, 0, 0);
      }
    }
  };

  // ---- stage 2 ----
  LDB(pB + 4 * 16384, B);
  zacc();
  pass(sH1);
  {
    float bv0 = b2[c0], bv1 = b2[c1];
    for (int mb = 0; mb < 4; ++mb)
      for (int i = 0; i < 4; ++i) {
        int r = 16 * mb + 4 * q + i;
        sH2[r][c0] = f2bf(geluf(acc[mb][0][i] + bv0));
        sH2[r][c1] = f2bf(geluf(acc[mb][1][i] + bv1));
      }
  }
  __syncthreads();  // B2

  // ---- stage 3 + LN partials ----
  LDB(pB + 5 * 16384, B);
  zacc();
  pass(sH2);
  {
    float bv0 = b3[c0], bv1 = b3[c1];
    for (int mb = 0; mb < 4; ++mb)
      for (int i = 0; i < 4; ++i) {
        float x0 = acc[mb][0][i] + bv0;
        float x1 = acc[mb][1][i] + bv1;
        acc[mb][0][i] = x0; acc[mb][1][i] = x1;
        float s = x0 + x1, s2 = x0 * x0 + x1 * x1;
        s += __shfl_xor(s, 1); s += __shfl_xor(s, 2);
        s += __shfl_xor(s, 4); s += __shfl_xor(s, 8);
        s2 += __shfl_xor(s2, 1); s2 += __shfl_xor(s2, 2);
        s2 += __shfl_xor(s2, 4); s2 += __shfl_xor(s2, 8);
        if (lr == 0) { sR1[w][16 * mb + 4 * q + i] = s; sR2[w][16 * mb + 4 * q + i] = s2; }
      }
  }
  __syncthreads();  // B3
  if (tid < 64) {
    float s = sR1[0][tid] + sR1[1][tid] + sR1[2][tid] + sR1[3][tid];
    float s2 = sR2[0][tid] + sR2[1][tid] + sR2[2][tid] + sR2[3][tid];
    float m = s * (1.f / 128.f);
    float v = s2 * (1.f / 128.f) - m * m;
    sM[tid] = m;
    sRS[tid] = rsqrtf(v + LN_EPS);
  }
  __syncthreads();  // B4

  {
    float lg0 = ln_g[c0], lg1 = ln_g[c1];
    float lb0 = ln_b[c0], lb1 = ln_b[c1];
    for (int mb = 0; mb < 4; ++mb)
      for (int i = 0; i < 4; ++i) {
        int r = 16 * mb + 4 * q + i;
        int dst = sDst[r];
        float m = sM[r], rs = sRS[r], gt = sGate[r];
        float v0 = ((acc[mb][0][i] - m) * rs * lg0 + lb0) * gt;
        float v1 = ((acc[mb][1][i] - m) * rs * lg1 + lb1) * gt;
        float o0 = __shfl_xor(v0, 1);
        float o1 = __shfl_xor(v1, 1);
        if (dst >= 0) {
          unsigned int pk;
          int colb;
          if ((lr & 1) == 0) {
            pk = (unsigned int)f2bf(v0) | ((unsigned int)f2bf(o0) << 16);
            colb = c0;
          } else {
            pk = (unsigned int)f2bf(o1) | ((unsigned int)f2bf(v1) << 16);
            colb = c0 + 15;
          }
          unsigned short* addr = upd + (long long)dst * 128 + colb;
          asm volatile("global_atomic_pk_add_bf16 %0, %1, off"
                       :: "v"(addr), "v"(pk) : "memory");
        }
      }
  }
}

// ---------------------------------------------------------------------------
extern "C" void kernel_launch(void* const* d_in, const int* in_sizes, int n_in,
                              void* d_out, int out_size, void* d_ws, size_t ws_size,
                              hipStream_t stream) {
  const float* feat   = (const float*)d_in[0];
  const int* edge_src = (const int*)d_in[1];
  const int* edge_dst = (const int*)d_in[2];
  const float* W_src = (const float*)d_in[3];  const float* b_src = (const float*)d_in[4];
  const float* W_dst = (const float*)d_in[5];  const float* b_dst = (const float*)d_in[6];
  const float* W1a = (const float*)d_in[7];    const float* W1b = (const float*)d_in[8];
  const float* b1  = (const float*)d_in[9];
  const float* W2  = (const float*)d_in[10];   const float* b2  = (const float*)d_in[11];
  const float* W3  = (const float*)d_in[12];   const float* b3  = (const float*)d_in[13];
  const float* ln_g = (const float*)d_in[14];  const float* ln_b = (const float*)d_in[15];
  const float* Wg1a = (const float*)d_in[16];  const float* Wg1b = (const float*)d_in[17];
  const float* bg1  = (const float*)d_in[18];
  const float* Wg2  = (const float*)d_in[19];  const float* bg2 = (const float*)d_in[20];
  const float* W_out = (const float*)d_in[21]; const float* b_out = (const float*)d_in[22];

  int N = in_sizes[0] / 128;   // 100000
  int E = in_sizes[1];         // 400000

  // ws: [wT 288KB][SrcCat bf16 N*256][DstCat bf16 N*256][upd bf16 N*128]
  char* ws = (char*)d_ws;
  unsigned short* wT = (unsigned short*)ws;
  size_t off = 9 * 16384 * sizeof(unsigned short);
  unsigned short* SrcCat = (unsigned short*)(ws + off);
  off += (size_t)N * 256 * sizeof(unsigned short);
  unsigned short* DstCat = (unsigned short*)(ws + off);
  off += (size_t)N * 256 * sizeof(unsigned short);
  unsigned short* upd = (unsigned short*)(ws + off);

  prep_weights<<<36, 256, 0, stream>>>(W_src, W_dst, W1a, W1b, W2, W3, Wg1a, Wg1b,
                                       W_out, wT);
  int mtiles = (N + 63) / 64;
  node_fused<<<dim3(mtiles, 2), 256, 0, stream>>>(feat, wT, b_src, b_dst, b1, bg1,
                                                  SrcCat, DstCat, upd, N);
  edge_fused<<<(E + 63) / 64, 256, 0, stream>>>(SrcCat, DstCat, edge_src, edge_dst,
                                                wT, b2, b3, ln_g, ln_b, Wg2, bg2,
                                                upd, E);
  gemm_out<<<mtiles, 256, 0, stream>>>(upd, wT + 8 * 16384, b_out, (float*)d_out, N);
}